// Round 11
// baseline (295.633 us; speedup 1.0000x reference)
//
#include <hip/hip_runtime.h>
#include <hip/hip_bf16.h>

#define NWIN 4096
#define NH 6
#define NTOK 64
#define CDIM 192
#define SCALE 0.17677669529663687f
#define LOG2E 1.4426950408889634f

typedef __attribute__((ext_vector_type(8))) short short8;
typedef __attribute__((ext_vector_type(4))) short short4v;
typedef __attribute__((ext_vector_type(4))) float f32x4;

#define MFMA32(A, B, C) __builtin_amdgcn_mfma_f32_16x16x32_bf16(A, B, C, 0, 0, 0)
#define MFMA16(A, B, C) __builtin_amdgcn_mfma_f32_16x16x16bf16_1k(A, B, C, 0, 0, 0)

__device__ __forceinline__ short bf(float x) {
  union { __hip_bfloat16 h; short s; } u;
  u.h = __float2bfloat16(x);
  return u.s;
}

__device__ __forceinline__ short8 cvt8v(f32x4 a, f32x4 b) {
  short8 r;
#pragma unroll
  for (int i = 0; i < 4; ++i) { r[i] = bf(a[i]); r[4 + i] = bf(b[i]); }
  return r;
}

// prep: weights -> bf16 (q rows scaled by SCALE*log2e); bias pre-gathered into
// the S^T fragment-coalesced layout biasS[h][slot(qh,nl,mt)][lane][4] * log2e;
// qkv_b copied with q-part scaled by SCALE*log2e.
__global__ void prep_weights(const float* __restrict__ qkv_w,
                             const float* __restrict__ proj_w,
                             const float* __restrict__ rel_tbl,
                             const float* __restrict__ qkv_b,
                             short* __restrict__ wbuf,
                             float* __restrict__ biasS,
                             float* __restrict__ qkvb2) {
  const int i = blockIdx.x * 256 + threadIdx.x;   // 963*256 = 246528
  if (i < 110592) {
    float v = qkv_w[i];
    if (i < 36864) v *= SCALE * LOG2E;
    wbuf[i] = bf(v);
  } else if (i < 147456) {
    wbuf[i] = bf(proj_w[i - 110592]);
  } else if (i < 245760) {
    const int j = i - 147456;            // [0, 98304) = 6 * 16384
    const int h = j >> 14;
    const int t = j & 16383;
    const int slot = t >> 10;            // (qh*2+nl)*4 + mt
    const int ln = (t >> 2) & 63;
    const int e = t & 3;
    const int qh = slot >> 3, nl = (slot >> 2) & 1, mt = slot & 3;
    const int n = qh * 32 + nl * 16 + (ln & 15);
    const int m = mt * 16 + (ln >> 4) * 4 + e;
    const int idx = ((n >> 3) - (m >> 3) + 7) * 15 + ((n & 7) - (m & 7) + 7);
    biasS[j] = rel_tbl[idx * NH + h] * LOG2E;
  } else {
    const int j = i - 245760;
    if (j < 576) qkvb2[j] = qkv_b[j] * (j < CDIM ? SCALE * LOG2E : 1.0f);
  }
}

#define LDAF(dst, kc) do {                                              \
  _Pragma("unroll")                                                     \
  for (int mt_ = 0; mt_ < 4; ++mt_) {                                   \
    const int r_ = mt_ * 16 + cc;                                       \
    dst[mt_] = *(const short8*)&lds[r_ * CDIM + ((kc) ^ ((r_ & 7) << 3))]; \
  } } while (0)

// ---- stage 1 for one head: q/k (swapped, transposed) + v (normal) fragments ----
__device__ __forceinline__ void stage1_head(
    const short* lds, const short* wall, const float* qkvb2,
    int h, int cc, int g,
    short4v qf[4][2], short4v kf[4][2], short4v vf[2][4]) {
  const short* wk_ = wall + CDIM * CDIM;
  const short* wv_ = wall + 2 * CDIM * CDIM;
  const int r0 = (h * 32 + cc) * CDIM;
  const int r1 = r0 + 16 * CDIM;

  // pass Q (swapped: lane cc = token)
  {
    f32x4 acc[2][4];
#pragma unroll
    for (int ft = 0; ft < 2; ++ft)
#pragma unroll
      for (int mt = 0; mt < 4; ++mt)
        acc[ft][mt] = (f32x4){0.f, 0.f, 0.f, 0.f};
#pragma unroll 1
    for (int ks = 0; ks < 6; ++ks) {
      const int c0 = ks * 32 + g * 8;
      short8 w0 = *(const short8*)&wall[r0 + c0];
      short8 w1 = *(const short8*)&wall[r1 + c0];
      short8 afr[4];
      LDAF(afr, c0);
#pragma unroll
      for (int mt = 0; mt < 4; ++mt) {
        acc[0][mt] = MFMA32(w0, afr[mt], acc[0][mt]);
        acc[1][mt] = MFMA32(w1, afr[mt], acc[1][mt]);
      }
    }
#pragma unroll
    for (int ft = 0; ft < 2; ++ft) {
      f32x4 qb = *(const f32x4*)&qkvb2[h * 32 + ft * 16 + g * 4];
#pragma unroll
      for (int nt = 0; nt < 4; ++nt)
#pragma unroll
        for (int j = 0; j < 4; ++j)
          qf[nt][ft][j] = bf(acc[ft][nt][j] + qb[j]);
    }
  }
  // pass K
  {
    f32x4 acc[2][4];
#pragma unroll
    for (int ft = 0; ft < 2; ++ft)
#pragma unroll
      for (int mt = 0; mt < 4; ++mt)
        acc[ft][mt] = (f32x4){0.f, 0.f, 0.f, 0.f};
#pragma unroll 1
    for (int ks = 0; ks < 6; ++ks) {
      const int c0 = ks * 32 + g * 8;
      short8 w0 = *(const short8*)&wk_[r0 + c0];
      short8 w1 = *(const short8*)&wk_[r1 + c0];
      short8 afr[4];
      LDAF(afr, c0);
#pragma unroll
      for (int mt = 0; mt < 4; ++mt) {
        acc[0][mt] = MFMA32(w0, afr[mt], acc[0][mt]);
        acc[1][mt] = MFMA32(w1, afr[mt], acc[1][mt]);
      }
    }
#pragma unroll
    for (int ft = 0; ft < 2; ++ft) {
      f32x4 kb = *(const f32x4*)&qkvb2[CDIM + h * 32 + ft * 16 + g * 4];
#pragma unroll
      for (int nt = 0; nt < 4; ++nt)
#pragma unroll
        for (int j = 0; j < 4; ++j)
          kf[nt][ft][j] = bf(acc[ft][nt][j] + kb[j]);
    }
  }
  // pass V (normal: lane cc = feature)
  {
    f32x4 acc[4][2];
#pragma unroll
    for (int mt = 0; mt < 4; ++mt)
#pragma unroll
      for (int dt = 0; dt < 2; ++dt)
        acc[mt][dt] = (f32x4){0.f, 0.f, 0.f, 0.f};
#pragma unroll 1
    for (int ks = 0; ks < 6; ++ks) {
      const int c0 = ks * 32 + g * 8;
      short8 w0 = *(const short8*)&wv_[r0 + c0];
      short8 w1 = *(const short8*)&wv_[r1 + c0];
      short8 afr[4];
      LDAF(afr, c0);
#pragma unroll
      for (int mt = 0; mt < 4; ++mt) {
        acc[mt][0] = MFMA32(afr[mt], w0, acc[mt][0]);
        acc[mt][1] = MFMA32(afr[mt], w1, acc[mt][1]);
      }
    }
    float vb0 = qkvb2[2 * CDIM + h * 32 + cc];
    float vb1 = qkvb2[2 * CDIM + h * 32 + 16 + cc];
#pragma unroll
    for (int kt = 0; kt < 4; ++kt)
#pragma unroll
      for (int j = 0; j < 4; ++j) {
        vf[0][kt][j] = bf(acc[kt][0][j] + vb0);
        vf[1][kt][j] = bf(acc[kt][1][j] + vb1);
      }
  }
}

// ---- attention for one head, fully in-register; output packed bf16 ----
__device__ __forceinline__ void attn_head(
    const float* biasS, int h, int lane,
    const short4v qf[4][2], const short4v kf[4][2], const short4v vf[2][4],
    short4v o[2][2][2]) {
  const float* bs = biasS + h * 16384;
#pragma unroll
  for (int qh = 0; qh < 2; ++qh) {
    f32x4 sacc[4][2];
#pragma unroll
    for (int mt = 0; mt < 4; ++mt)
#pragma unroll
      for (int nl = 0; nl < 2; ++nl) {
        f32x4 z = *(const f32x4*)&bs[(((qh * 2 + nl) << 2) + mt) * 1024 + lane * 4];
        z = MFMA16(kf[mt][0], qf[qh * 2 + nl][0], z);
        sacc[mt][nl] = MFMA16(kf[mt][1], qf[qh * 2 + nl][1], z);
      }
    // softmax: p = exp2(s), log2e pre-folded; no max-subtract (|s| small, fp32-safe)
    short4v pf[2][4];
#pragma unroll
    for (int nl = 0; nl < 2; ++nl) {
      float sum = 0.f;
#pragma unroll
      for (int mt = 0; mt < 4; ++mt)
#pragma unroll
        for (int e = 0; e < 4; ++e) {
          float p = exp2f(sacc[mt][nl][e]);
          sacc[mt][nl][e] = p;
          sum += p;
        }
      sum += __shfl_xor(sum, 16);
      sum += __shfl_xor(sum, 32);
      const float rinv = __builtin_amdgcn_rcpf(sum);
#pragma unroll
      for (int kt = 0; kt < 4; ++kt)
#pragma unroll
        for (int j = 0; j < 4; ++j)
          pf[nl][kt][j] = bf(sacc[kt][nl][j] * rinv);
    }
    // PV
#pragma unroll
    for (int nl = 0; nl < 2; ++nl)
#pragma unroll
      for (int dt = 0; dt < 2; ++dt) {
        f32x4 z = (f32x4){0.f, 0.f, 0.f, 0.f};
#pragma unroll
        for (int kt = 0; kt < 4; ++kt)
          z = MFMA16(pf[nl][kt], vf[dt][kt], z);
#pragma unroll
        for (int e = 0; e < 4; ++e)
          o[qh][nl][dt][e] = bf(z[e]);
      }
  }
}

__device__ __forceinline__ void write_ao(short* lds, int h, int g, int cc,
                                         const short4v o[2][2][2]) {
#pragma unroll
  for (int qh = 0; qh < 2; ++qh)
#pragma unroll
    for (int nl = 0; nl < 2; ++nl)
#pragma unroll
      for (int dt = 0; dt < 2; ++dt)
#pragma unroll
        for (int e = 0; e < 4; ++e) {
          const int r = qh * 32 + nl * 16 + g * 4 + e;
          const int c = h * 32 + dt * 16 + cc;
          lds[r * CDIM + (c ^ ((r & 7) << 3))] = o[qh][nl][dt][e];
        }
}

// 192 threads = 3 waves; each wave handles 2 heads sequentially.
// 3-wave blocks pack the 16-wave-slot/CU budget as 5 blocks (15 waves) vs the
// 6-wave shape's 2 blocks (12 waves).
__global__ __launch_bounds__(192, 4)
void swin_block_kernel(const float* __restrict__ x,
                       const short* __restrict__ wall,   // qkv bf16 | proj bf16
                       const float* __restrict__ qkvb2,  // q-part pre-scaled (incl log2e)
                       const float* __restrict__ proj_b,
                       const float* __restrict__ biasS,  // [6][16][64][4] f32 frag layout
                       float* __restrict__ out) {
  __shared__ __align__(16) short lds[12288];   // 24576 B: x tile, later ao tile

  const int b = blockIdx.x;
  const int tid = threadIdx.x;   // 0..191
  const int wv = tid >> 6;       // wave 0..2
  const int lane = tid & 63;
  const int g = lane >> 4;
  const int cc = lane & 15;
  const int h0 = wv * 2;         // this wave's two heads: h0, h0+1

  const float* xp = x + (size_t)b * (NTOK * CDIM);

  // ---------------- stage 0: cooperative x -> bf16 LDS (swizzled) ----------------
#pragma unroll
  for (int it = 0; it < 4; ++it) {
    const int flat = (tid + it * 192) * 16;
    const int r = flat / CDIM;
    const int c = flat % CDIM;
    const int X = (r & 7) << 3;
    f32x4 a0 = *(const f32x4*)(xp + flat);
    f32x4 a1 = *(const f32x4*)(xp + flat + 4);
    f32x4 a2 = *(const f32x4*)(xp + flat + 8);
    f32x4 a3 = *(const f32x4*)(xp + flat + 12);
    *(short8*)&lds[r * CDIM + (c ^ X)] = cvt8v(a0, a1);
    *(short8*)&lds[r * CDIM + ((c + 8) ^ X)] = cvt8v(a2, a3);
  }
  __syncthreads();

  // ---------------- head A: QKV + attention (output held in 16 regs) ----------------
  short4v oA[2][2][2];
  {
    short4v qf[4][2], kf[4][2], vf[2][4];
    stage1_head(lds, wall, qkvb2, h0, cc, g, qf, kf, vf);
    attn_head(biasS, h0, lane, qf, kf, vf, oA);
  }

  // ---------------- head B: QKV (last use of x tile) ----------------
  short4v qfB[4][2], kfB[4][2], vfB[2][4];
  stage1_head(lds, wall, qkvb2, h0 + 1, cc, g, qfB, kfB, vfB);

  __syncthreads();   // x tile dead block-wide -> lds becomes ao

  write_ao(lds, h0, g, cc, oA);
  {
    short4v oB[2][2][2];
    attn_head(biasS, h0 + 1, lane, qfB, kfB, vfB, oB);
    write_ao(lds, h0 + 1, g, cc, oB);
  }
  __syncthreads();

  // ---------------- stage 3: output projection (swapped), 4 jt-tiles/wave ----------------
  // pacc[mt][jt]: row g*4+e = feature wv*64+jt*16+g*4+e, col cc = token mt*16+cc
  const short* wp_ = wall + 3 * CDIM * CDIM;
  const int rp0 = (wv * 64 + cc) * CDIM;
  f32x4 pacc[4][4];
#pragma unroll
  for (int mt = 0; mt < 4; ++mt)
#pragma unroll
    for (int jt = 0; jt < 4; ++jt)
      pacc[mt][jt] = (f32x4){0.f, 0.f, 0.f, 0.f};

#pragma unroll 1
  for (int ks = 0; ks < 6; ++ks) {
    const int c0 = ks * 32 + g * 8;
    short8 p0 = *(const short8*)&wp_[rp0 + c0];
    short8 p1 = *(const short8*)&wp_[rp0 + 16 * CDIM + c0];
    short8 p2 = *(const short8*)&wp_[rp0 + 32 * CDIM + c0];
    short8 p3 = *(const short8*)&wp_[rp0 + 48 * CDIM + c0];
    short8 afr[4];
    LDAF(afr, c0);
#pragma unroll
    for (int mt = 0; mt < 4; ++mt) {
      pacc[mt][0] = MFMA32(p0, afr[mt], pacc[mt][0]);
      pacc[mt][1] = MFMA32(p1, afr[mt], pacc[mt][1]);
      pacc[mt][2] = MFMA32(p2, afr[mt], pacc[mt][2]);
      pacc[mt][3] = MFMA32(p3, afr[mt], pacc[mt][3]);
    }
  }

  // ---------------- epilogue: coalesced f32x4 stores ----------------
  float* op = out + (size_t)b * (NTOK * CDIM);
  f32x4 pbv[4];
#pragma unroll
  for (int jt = 0; jt < 4; ++jt)
    pbv[jt] = *(const f32x4*)&proj_b[wv * 64 + jt * 16 + g * 4];
#pragma unroll
  for (int mt = 0; mt < 4; ++mt)
#pragma unroll
    for (int jt = 0; jt < 4; ++jt) {
      f32x4 v = pacc[mt][jt] + pbv[jt];
      *(f32x4*)&op[(mt * 16 + cc) * CDIM + wv * 64 + jt * 16 + g * 4] = v;
    }
}

extern "C" void kernel_launch(void* const* d_in, const int* in_sizes, int n_in,
                              void* d_out, int out_size, void* d_ws, size_t ws_size,
                              hipStream_t stream) {
  const float* x       = (const float*)d_in[0];
  const float* qkv_w   = (const float*)d_in[1];
  const float* qkv_b   = (const float*)d_in[2];
  const float* proj_w  = (const float*)d_in[3];
  const float* proj_b  = (const float*)d_in[4];
  const float* rel_tbl = (const float*)d_in[5];
  float* out = (float*)d_out;

  short* wbuf  = (short*)d_ws;                    // 147456 shorts = 294912 B
  float* biasS = (float*)(wbuf + 147456);         // 98304 floats = 393216 B
  float* qkvb2 = biasS + 98304;                   // 576 floats

  prep_weights<<<963, 256, 0, stream>>>(qkv_w, proj_w, rel_tbl, qkv_b,
                                        wbuf, biasS, qkvb2);
  swin_block_kernel<<<NWIN, 192, 0, stream>>>(x, wbuf, qkvb2, proj_b, biasS, out);
}